// Round 11
// baseline (173.033 us; speedup 1.0000x reference)
//
#include <hip/hip_runtime.h>
#include <hip/hip_bf16.h>

// Problem constants (fixed): coords (2, 4096, 3) float32, num_k = 30.
// Outputs: one flat FLOAT32 buffer, reference return order (rounds 3/4).
// f32 input confirmed rounds 4-10; bf16 hedge removed.
//
// R11 structure (R7-R10 post-mortems: dur moves only with phase-1 work):
//   Kernel 1: bucket points by x into 4096 buckets (counting scatter; order
//             within bucket arbitrary -> selection is order-independent).
//   Kernel 2: per row, scan a bucket-snapped rank window (~1280 candidates
//             instead of 4096), exact top-30 by lex (d, j), then verify
//             coverage via bucket-edge arithmetic; expand + re-select (from
//             saved pristine caches) in the rare uncovered case. Exact.
constexpr int B = 2;
constexpr int N = 4096;
constexpr int K = 30;
constexpr int NBKT = 4096;
constexpr float XMIN = -48.0f;
constexpr float XRANGE = 96.0f;
constexpr float BKT_H = XRANGE / (float)NBKT;   // 3/128, exact in f32
constexpr int W0 = 640;    // initial half-window (slots)
constexpr int WEXP = 512;  // expansion step (slots)

constexpr size_t OFF_POS = 0;                                   // B*N*K*16
constexpr size_t OFF_AD  = OFF_POS + (size_t)B * N * K * 16;    // B*N*3
constexpr size_t OFF_O   = OFF_AD  + (size_t)B * N * 3;         // B*N*K*3
constexpr size_t OFF_GS  = OFF_O   + (size_t)B * N * K * 3;     // B*N*K*15
constexpr size_t OFF_DN  = OFF_GS  + (size_t)B * N * K * 15;    // B*N*K
constexpr size_t OFF_E   = OFF_DN  + (size_t)B * N * K;         // B*N*K

constexpr float BIGD = 1e30f;               // d identity (real d < 300)
constexpr unsigned int BIGF = 0xFFFFFFFFu;  // jf identity

// ws layout per batch (4-byte elements): xs ys zs js rank slotBucket (4096 each),
// bucketStart (4097). Stride padded to 28680 elems -> 229 KB total for B=2.
constexpr size_t WS_STRIDE = 7 * 4096 + 8;

struct WsB { float *xs, *ys, *zs; int *js, *rank, *sb, *bstart; };
__device__ __forceinline__ WsB wsb(void* ws, int b) {
  float* base = (float*)ws + (size_t)b * WS_STRIDE;
  WsB w;
  w.xs = base; w.ys = base + 4096; w.zs = base + 8192;
  w.js = (int*)(base + 12288); w.rank = (int*)(base + 16384);
  w.sb = (int*)(base + 20480); w.bstart = (int*)(base + 24576);
  return w;
}

__device__ __forceinline__ int bucketOf(float x) {
  int t = (int)((x - XMIN) * ((float)NBKT / XRANGE));
  return t < 0 ? 0 : (t > NBKT - 1 ? NBKT - 1 : t);
}

struct F3 { float x, y, z; };   // 12B -> dwordx3

// np-exact f32 distance, no FMA. Scan and refill MUST share this definition.
__device__ __forceinline__ float dist_core(float px, float py, float pz,
                                           float xi, float yi, float zi) {
#pragma clang fp contract(off)
  const float dx = px - xi;
  const float dy = py - yi;
  const float dz = pz - zi;
  return sqrtf(((dx * dx + dy * dy) + dz * dz) + 1e-6f);
}

// ---- DPP 64-lane min reductions (proven R7-R10) --------------------------
template <int CTRL>
__device__ __forceinline__ float dpp_min_f32(float v) {
  const int mv = __builtin_amdgcn_update_dpp(__float_as_int(BIGD), __float_as_int(v),
                                             CTRL, 0xF, 0xF, false);
  return fminf(__int_as_float(mv), v);
}
template <int CTRL>
__device__ __forceinline__ unsigned int dpp_min_u32(unsigned int v) {
  const unsigned int mv = (unsigned int)__builtin_amdgcn_update_dpp(
      (int)BIGF, (int)v, CTRL, 0xF, 0xF, false);
  return mv < v ? mv : v;
}
__device__ __forceinline__ float wave_min_f32_bcast(float v) {
  v = dpp_min_f32<0x111>(v);
  v = dpp_min_f32<0x112>(v);
  v = dpp_min_f32<0x114>(v);
  v = dpp_min_f32<0x118>(v);
  v = dpp_min_f32<0x142>(v);
  v = dpp_min_f32<0x143>(v);
  return __int_as_float(__builtin_amdgcn_readlane(__float_as_int(v), 63));
}
__device__ __forceinline__ unsigned int wave_min_u32_bcast(unsigned int v) {
  v = dpp_min_u32<0x111>(v);
  v = dpp_min_u32<0x112>(v);
  v = dpp_min_u32<0x114>(v);
  v = dpp_min_u32<0x118>(v);
  v = dpp_min_u32<0x142>(v);
  v = dpp_min_u32<0x143>(v);
  return (unsigned int)__builtin_amdgcn_readlane((int)v, 63);
}

// Lex (d, jf) argmin over heads; jf = (j_orig<<6)|chunk so u32 order on jf is
// j_orig-major -> matches jax.lax.top_k stable (d, j) order exactly.
__device__ __forceinline__ void pop_argmin(float d0, unsigned int f0,
                                           float& dmin, unsigned int& fmin) {
  dmin = wave_min_f32_bcast(d0);
  const unsigned long long tie = __ballot(d0 == dmin);
  if (__popcll(tie) == 1) {
    fmin = (unsigned int)__builtin_amdgcn_readlane((int)f0, __ffsll(tie) - 1);
  } else {
    fmin = wave_min_u32_bcast((d0 == dmin) ? f0 : BIGF);
  }
}

// Tie-aware sorted-3 insert on lex (d, jf). Within-lane enumeration order is
// arbitrary (bucket scatter), so ties MUST compare jf.
__device__ __forceinline__ void insert3(float d, unsigned int jf,
                                        float& d0, float& d1, float& d2,
                                        unsigned int& f0, unsigned int& f1, unsigned int& f2) {
  const bool lt2 = (d < d2) || (d == d2 && jf < f2);
  const bool lt1 = (d < d1) || (d == d1 && jf < f1);
  const bool lt0 = (d < d0) || (d == d0 && jf < f0);
  const float        nd2 = lt1 ? d1 : (lt2 ? d : d2);
  const unsigned int nf2 = lt1 ? f1 : (lt2 ? jf : f2);
  const float        nd1 = lt0 ? d0 : (lt1 ? d : d1);
  const unsigned int nf1 = lt0 ? f0 : (lt1 ? jf : f1);
  const float        nd0 = lt0 ? d : d0;
  const unsigned int nf0 = lt0 ? jf : f0;
  d2 = nd2; f2 = nf2; d1 = nd1; f1 = nf1; d0 = nd0; f0 = nf0;
}

// range-reduce to |r| <= pi, then native sin/cos (safe hw domain)
__device__ __forceinline__ float red2pi(float x) {
  return x - 6.28318530718f * rintf(x * 0.15915494309f);
}

__device__ __forceinline__ void norm3(float& x, float& y, float& z) {
  float n = sqrtf((x * x + y * y) + z * z);
  n = fmaxf(n, 1e-12f);
  x /= n; y /= n; z /= n;
}

__device__ __forceinline__ void cross3(float ax, float ay, float az,
                                       float bx, float by, float bz,
                                       float& cx, float& cy, float& cz) {
  cx = ay * bz - az * by;
  cy = az * bx - ax * bz;
  cz = ax * by - ay * bx;
}

// ---- Kernel 1: counting-bucket build (one block per batch) ---------------
__global__ __launch_bounds__(1024)
void build_kernel(const float* __restrict__ X, void* __restrict__ ws) {
  __shared__ unsigned int cnt[NBKT];
  __shared__ unsigned int tmp[NBKT];
  const int b = blockIdx.x;
  const int tid = threadIdx.x;
  const float* __restrict__ Xb = X + (size_t)b * N * 3;
  WsB w = wsb(ws, b);

#pragma unroll
  for (int e = 0; e < 4; ++e) cnt[e * 1024 + tid] = 0;
  __syncthreads();
#pragma unroll
  for (int e = 0; e < 4; ++e) {
    const int j = e * 1024 + tid;
    atomicAdd(&cnt[bucketOf(Xb[j * 3])], 1u);
  }
  __syncthreads();
  // inclusive Hillis-Steele scan over 4096 (ping-pong)
  unsigned int* src = cnt;
  unsigned int* dst = tmp;
  for (int off = 1; off < NBKT; off <<= 1) {
#pragma unroll
    for (int e = 0; e < 4; ++e) {
      const int j = e * 1024 + tid;
      unsigned int v = src[j];
      if (j >= off) v += src[j - off];
      dst[j] = v;
    }
    __syncthreads();
    unsigned int* t = src; src = dst; dst = t;
  }
  // exclusive scan -> global bucketStart + running offsets for scatter
#pragma unroll
  for (int e = 0; e < 4; ++e) {
    const int j = e * 1024 + tid;
    const unsigned int ex = (j == 0) ? 0u : src[j - 1];
    dst[j] = ex;
    w.bstart[j] = (int)ex;
  }
  if (tid == 0) w.bstart[NBKT] = N;
  __syncthreads();
#pragma unroll
  for (int e = 0; e < 4; ++e) {
    const int j = e * 1024 + tid;
    const float x = Xb[j * 3];
    const int bkt = bucketOf(x);
    const int slot = (int)atomicAdd(&dst[bkt], 1u);
    w.xs[slot] = x;
    w.ys[slot] = Xb[j * 3 + 1];
    w.zs[slot] = Xb[j * 3 + 2];
    w.js[slot] = j;
    w.rank[j] = slot;
    w.sb[slot] = bkt;
  }
}

// ---- Kernel 2: per-row windowed top-30 + features ------------------------
__device__ __forceinline__ void scan_range(const WsB& w, int a, int bnd, int lane,
                                           float qx, float qy, float qz,
                                           float& d0, float& d1, float& d2,
                                           unsigned int& f0, unsigned int& f1, unsigned int& f2) {
  const int cb = a >> 6, ce = (bnd + 63) >> 6;   // absolute chunks (<=64)
  for (int c = cb; c < ce; ++c) {
    const int s = c * 64 + lane;                 // s <= 4095 always: safe load
    const float x = w.xs[s], y = w.ys[s], z = w.zs[s];
    const int jo = w.js[s];
    float d = dist_core(x, y, z, qx, qy, qz);
    unsigned int jf = ((unsigned int)jo << 6) | (unsigned int)c;
    if (s < a || s >= bnd) { d = BIGD; jf = BIGF; }
    insert3(d, jf, d0, d1, d2, f0, f1, f2);
  }
}

__global__ __launch_bounds__(256)
void protein_feat_kernel(const float* __restrict__ X,
                         float* __restrict__ out,
                         void* __restrict__ ws) {
  const int lane = threadIdx.x & 63;
  const int wv   = threadIdx.x >> 6;
  const int row  = blockIdx.x * 4 + wv;   // one wave per row
  const int b    = row >> 12;
  const int i    = row & (N - 1);
  const WsB w = wsb(ws, b);
  const float* __restrict__ Xb = X + (size_t)b * N * 3;

  const float qx = Xb[i * 3 + 0];
  const float qy = Xb[i * 3 + 1];
  const float qz = Xb[i * 3 + 2];

  // ---- initial bucket-snapped window around this row's slot ----
  const int p = w.rank[i];
  int t_lo = p - W0; if (t_lo < 0) t_lo = 0;
  int t_hi = p + W0; if (t_hi > N) t_hi = N;
  int blo = w.sb[t_lo];
  int bhi = w.sb[t_hi - 1] + 1;
  int slo = w.bstart[blo];
  int shi = w.bstart[bhi];

  float d0 = BIGD, d1 = BIGD, d2 = BIGD;
  unsigned int f0 = BIGF, f1 = BIGF, f2 = BIGF;
  scan_range(w, slo, shi, lane, qx, qy, qz, d0, d1, d2, f0, f1, f2);

  int   sjv = 0;      // lane k (<K): neighbor k's original index
  float sdv = 0.0f;   // lane k (<K): neighbor k's distance
  for (;;) {
    // save pristine caches (expansion path restores them for exact re-select)
    const float sd0 = d0, sd1 = d1, sd2 = d2;
    const unsigned int sf0 = f0, sf1 = f1, sf2 = f2;
    unsigned long long exm = 0;   // consumed chunks within this lane's residue
    float d30 = 0.0f;
    for (int k = 0; k < K; ++k) {
      float dmin; unsigned int fmin;
      pop_argmin(d0, f0, dmin, fmin);
      if (lane == k) { sjv = (int)(fmin >> 6); sdv = dmin; }
      d30 = dmin;   // wave-uniform; last iteration = 30th distance
      const unsigned long long wb = __ballot(d0 == dmin && f0 == fmin);
      const int wl = __ffsll(wb) - 1;        // unique winner lane
      const int cw = (int)(fmin & 63u);      // winner's chunk
      if (lane == wl) {
        exm |= (1ull << cw);
        d0 = d1; f0 = f1; d1 = d2; f1 = f2; d2 = BIGD; f2 = BIGF;
      }
      if (__ballot(d0 == BIGD) != 0ull) {    // rare: winner lane's cache empty
        const unsigned int mlo = (unsigned int)__builtin_amdgcn_readlane((int)(unsigned int)(exm & 0xFFFFFFFFull), wl);
        const unsigned int mhi = (unsigned int)__builtin_amdgcn_readlane((int)(unsigned int)(exm >> 32), wl);
        const unsigned long long m = ((unsigned long long)mhi << 32) | mlo;
        const int s = lane * 64 + wl;        // lane t rescans chunk t of lane wl
        const float x = w.xs[s], y = w.ys[s], z = w.zs[s];
        const int jo = w.js[s];
        float dc = dist_core(x, y, z, qx, qy, qz);
        unsigned int fc = ((unsigned int)jo << 6) | (unsigned int)lane;
        if (s < slo || s >= shi || ((m >> lane) & 1ull)) { dc = BIGD; fc = BIGF; }
        float dm2; unsigned int fm2;
        pop_argmin(dc, fc, dm2, fm2);
        if (lane == wl) { d0 = dm2; f0 = fm2; }
      }
    }
    // ---- coverage check: unscanned points have x-gap > d30 (robust margin) ----
    const bool covL = (slo == 0) || ((qx - (XMIN + (float)blo * BKT_H)) > d30 + 1e-4f);
    const bool covR = (shi == N) || (((XMIN + (float)bhi * BKT_H) - qx) > d30 + 1e-4f);
    if (covL && covR) break;
    // restore caches, expand both sides, re-select
    d0 = sd0; d1 = sd1; d2 = sd2; f0 = sf0; f1 = sf1; f2 = sf2;
    int nlo_t = slo - WEXP; if (nlo_t < 0) nlo_t = 0;
    int nhi_t = shi + WEXP; if (nhi_t > N) nhi_t = N;
    const int nblo = w.sb[nlo_t];
    const int nbhi = w.sb[nhi_t - 1] + 1;
    const int nslo = w.bstart[nblo];
    const int nshi = w.bstart[nbhi];
    if (nslo < slo) scan_range(w, nslo, slo, lane, qx, qy, qz, d0, d1, d2, f0, f1, f2);
    if (nshi > shi) scan_range(w, shi, nshi, lane, qx, qy, qz, d0, d1, d2, f0, f1, f2);
    slo = nslo; blo = nblo; shi = nshi; bhi = nbhi;
  }

  // ---- Row-uniform AD features and frame O3 (all lanes redundantly). ----
  float ad0 = 0.f, ad1 = 0.f, ad2 = 0.f;
  float o00 = 0.f, o01 = 0.f, o02 = 0.f;
  float o10 = 0.f, o11 = 0.f, o12 = 0.f;
  float o20 = 0.f, o21 = 0.f, o22 = 0.f;
  if (i >= 1 && i <= N - 3) {
    const float ax = Xb[(i - 1) * 3 + 0], ay = Xb[(i - 1) * 3 + 1], az = Xb[(i - 1) * 3 + 2];
    const float cx = Xb[(i + 1) * 3 + 0], cy = Xb[(i + 1) * 3 + 1], cz = Xb[(i + 1) * 3 + 2];
    const float ex = Xb[(i + 2) * 3 + 0], ey = Xb[(i + 2) * 3 + 1], ez = Xb[(i + 2) * 3 + 2];
    float u2x = qx - ax, u2y = qy - ay, u2z = qz - az; norm3(u2x, u2y, u2z);
    float u1x = cx - qx, u1y = cy - qy, u1z = cz - qz; norm3(u1x, u1y, u1z);
    float u0x = ex - cx, u0y = ey - cy, u0z = ez - cz; norm3(u0x, u0y, u0z);
    float n2x, n2y, n2z; cross3(u2x, u2y, u2z, u1x, u1y, u1z, n2x, n2y, n2z); norm3(n2x, n2y, n2z);
    float n1x, n1y, n1z; cross3(u1x, u1y, u1z, u0x, u0y, u0z, n1x, n1y, n1z); norm3(n1x, n1y, n1z);
    const float dotu = (u1x * u0x + u1y * u0y) + u1z * u0z;
    const float cosA = fminf(fmaxf(-dotu, -1.0f + 1e-6f), 1.0f - 1e-6f);
    const float A = acosf(cosA);
    const float dotn = (n2x * n1x + n2y * n1y) + n2z * n1z;
    const float cosD = fminf(fmaxf(dotn, -1.0f + 1e-6f), 1.0f - 1e-6f);
    const float du2n1 = (u2x * n1x + u2y * n1y) + u2z * n1z;
    const float sg = (du2n1 > 0.f) ? 1.f : ((du2n1 < 0.f) ? -1.f : 0.f);
    const float Dang = sg * acosf(cosD);
    const float sA = __sinf(A),    cA = __cosf(A);
    const float sD = __sinf(Dang), cD = __cosf(Dang);
    ad0 = cA; ad1 = sA * cD; ad2 = sA * sD;
    float o1x = u2x - u1x, o1y = u2y - u1y, o1z = u2z - u1z; norm3(o1x, o1y, o1z);
    o00 = o1x; o01 = o1y; o02 = o1z;
    o10 = n2x; o11 = n2y; o12 = n2z;
    cross3(o1x, o1y, o1z, n2x, n2y, n2z, o20, o21, o22);
  }

  const int rw = b * N + i;

  // ---- pos_emb: 480 contiguous values; p' = idx & 15 loop-invariant. ----
  {
    const size_t base = OFF_POS + (size_t)rw * (K * 16);
    const int pp = lane & 15;
    const float fr = __expf((float)((pp & 7) * 2) * -0.57564627f);
    const bool is_cos = (pp < 8);
#pragma unroll
    for (int it = 0; it < 8; ++it) {
      const int idx = it * 64 + lane;
      const int k = (idx >> 4) < K ? (idx >> 4) : (K - 1);
      const int jk = __shfl(sjv, k, 64);
      const float df = (float)(jk - i);
      const float r = red2pi(df * fr);
      const float v = is_cos ? __cosf(r) : __sinf(r);
      if (idx < K * 16) out[base + idx] = v;
    }
  }

  // ---- gs_d: 450 contiguous values. ----
  {
    const size_t base = OFF_GS + (size_t)rw * (K * 15);
#pragma unroll
    for (int it = 0; it < 8; ++it) {
      const int idx = it * 64 + lane;
      const int kq = idx / 15;
      const int k = kq < K ? kq : (K - 1);
      const int m = idx - kq * 15;
      const float d = __shfl(sdv, k, 64);
      const float mu = (float)(m * (20.0 / 14.0));
      const float q = (d - mu) / 1.3333334f;
      const float v = __expf(-(q * q));
      if (idx < K * 15) out[base + idx] = v;
    }
  }

  // ---- E_idx, D_neighbors, O_features on lanes < K; AD on 30..32. ----
  if (lane < K) {
    const size_t rowk = (size_t)rw * K + lane;
    const int j = sjv;
    out[OFF_E  + rowk] = (float)j;
    out[OFF_DN + rowk] = sdv;

    const F3 pt = ((const F3*)Xb)[j];
    const float gx = pt.x - qx, gy = pt.y - qy, gz = pt.z - qz;
    const float v0 = (o00 * gx + o01 * gy) + o02 * gz;
    const float v1 = (o10 * gx + o11 * gy) + o12 * gz;
    const float v2 = (o20 * gx + o21 * gy) + o22 * gz;
    const float nn = fmaxf(sqrtf((v0 * v0 + v1 * v1) + v2 * v2), 1e-12f);
    out[OFF_O + rowk * 3 + 0] = v0 / nn;
    out[OFF_O + rowk * 3 + 1] = v1 / nn;
    out[OFF_O + rowk * 3 + 2] = v2 / nn;
  } else if (lane < K + 3) {
    const int c = lane - K;
    const float v = (c == 0) ? ad0 : (c == 1) ? ad1 : ad2;
    out[OFF_AD + (size_t)rw * 3 + c] = v;
  }
}

extern "C" void kernel_launch(void* const* d_in, const int* in_sizes, int n_in,
                              void* d_out, int out_size, void* d_ws, size_t ws_size,
                              hipStream_t stream) {
  const float* X = (const float*)d_in[0];
  float* out = (float*)d_out;
  (void)in_sizes; (void)n_in; (void)out_size; (void)ws_size;  // needs ~230 KB of ws
  build_kernel<<<dim3(B), dim3(1024), 0, stream>>>(X, d_ws);
  protein_feat_kernel<<<dim3(B * N / 4), dim3(256), 0, stream>>>(X, out, d_ws);
}